// Round 6
// baseline (23.611 us; speedup 1.0000x reference)
//
#include <hip/hip_runtime.h>

#define TWO_PI 6.2831853071795864769f

// ws layout (bytes):
//   C    f32[393216]      @ 0         (1572864)   C = P1 + 0.975*P3
//   cnt  int[16]          @ 1572864
//   wde  int[6][2048]     @ 1572928   (49152)     winner (d<<8)|e per b
//   wv   f32[3][6][2048]  @ 1622080   (147456)    per-stage corrections val-P1
// total ~1.77 MB

// Kernel 1: blocks 0..95 build C (float4); block 96 resolves last-write-wins
// winners for ALL b via one 32-bit LDS hash: entry = ((key<<3|b)<<12)|k where
// key=(d<<8)|e, atomicMax over k = last write (np scatter semantics).
// Winners -> per-b correction lists in ws.
// pk layout: (b<<24)|(c<<16)|(d<<8)|e  =>  key = v & 0xFFFF  (r5 bug: used
// (v>>8)&0xFFFF = (c<<8)|d -> garbage positions, absmax 1e4).
__global__ __launch_bounds__(1024) void prep_kernel(
    const float* __restrict__ P1, const float* __restrict__ P3,
    const int* __restrict__ p5, const int* __restrict__ p6,
    const int* __restrict__ p7, const int* __restrict__ p8,
    const float* __restrict__ T4, const float* __restrict__ T11,
    const float* __restrict__ T14,
    float* __restrict__ C, int* __restrict__ cnt,
    int* __restrict__ wde_g, float* __restrict__ wv_g, int K)
{
    const int tid = (int)threadIdx.x;
    const int blk = (int)blockIdx.x;
    if (blk < 96) {                       // 96*1024 float4 = 393216 floats
        int i = blk * 1024 + tid;
        float4 a = ((const float4*)P1)[i];
        float4 c = ((const float4*)P3)[i];
        float4 r;
        r.x = fmaf(c.x, 0.975f, a.x);
        r.y = fmaf(c.y, 0.975f, a.y);
        r.z = fmaf(c.z, 0.975f, a.z);
        r.w = fmaf(c.w, 0.975f, a.w);
        ((float4*)C)[i] = r;
        return;
    }

    __shared__ unsigned pk[2048];         // (b<<24)|(c<<16)|(d<<8)|e
    __shared__ unsigned hmap[4096];
    __shared__ int scnt[8];
    for (int k = tid; k < K; k += 1024)
        pk[k] = ((unsigned)p5[k] << 24) | ((unsigned)p6[k] << 16) |
                ((unsigned)p7[k] << 8) | (unsigned)p8[k];
    for (int i = tid; i < 4096; i += 1024) hmap[i] = 0xFFFFFFFFu;
    if (tid < 8) scnt[tid] = 0;
    __syncthreads();

    for (int k = tid; k < K; k += 1024) {
        unsigned v = pk[k];
        unsigned key  = v & 0xFFFFu;                    // (d<<8)|e
        unsigned full = (key << 3) | (v >> 24);         // 19 bits: (d,e,b)
        unsigned mine = (full << 12) | (unsigned)k;     // k < 4096
        unsigned hh = (full * 2654435761u) >> 20;       // [0,4096)
        for (;;) {
            unsigned prev = atomicCAS(&hmap[hh], 0xFFFFFFFFu, mine);
            if (prev == 0xFFFFFFFFu) break;
            if ((prev >> 12) == full) { atomicMax(&hmap[hh], mine); break; }
            hh = (hh + 1) & 4095u;
        }
    }
    __syncthreads();

    for (int k = tid; k < K; k += 1024) {
        unsigned v = pk[k];
        unsigned key  = v & 0xFFFFu;
        unsigned full = (key << 3) | (v >> 24);
        unsigned hh = (full * 2654435761u) >> 20;
        unsigned cur;
        for (;;) {
            cur = hmap[hh];
            if ((cur >> 12) == full) break;
            hh = (hh + 1) & 4095u;
        }
        if ((cur & 0xFFFu) == (unsigned)k) {          // last write wins
            int b = (int)(v >> 24), c = (int)((v >> 16) & 0xFFu);
            float p1v = P1[(b << 16) | key];          // b*65536 + d*256 + e
            int w = atomicAdd(&scnt[b], 1);
            wde_g[b * 2048 + w] = (int)key;
            wv_g[(0 * 6 + b) * 2048 + w] = T4 [b * 256 + c] - p1v;
            wv_g[(1 * 6 + b) * 2048 + w] = T11[b * 256 + c] - p1v;
            wv_g[(2 * 6 + b) * 2048 + w] = T14[b * 256 + c] - p1v;
        }
    }
    __syncthreads();
    if (tid < 8) cnt[tid] = scnt[tid];
}

// Kernel 2: one block per (h,b) chain, 72 x 1024. thread=(dg 0..15, eg 0..63)
// register-caches C[dg*16+i][eg*4..+3] (16 float4 = 256KB/block). 3 stages:
// matvec from regs -> single-step 16->1 LDS reduce with modulation folded ->
// sparse corrections via LDS atomics (also modl-folded) -> ping-pong v.
__global__ __launch_bounds__(1024, 4) void chain_kernel(
    const float* __restrict__ C, const float* __restrict__ P2,
    const int* __restrict__ cnt, const int* __restrict__ wde_g,
    const float* __restrict__ wv_g,
    const float* __restrict__ f1, const float* __restrict__ ph1,
    const float* __restrict__ f2, const float* __restrict__ ph2,
    const float* __restrict__ f3, const float* __restrict__ ph3,
    float* __restrict__ out)
{
    __shared__ float vbuf[2][256];
    __shared__ float pv[16][256];
    __shared__ float modl[3][256];
    __shared__ int   wde[2048];
    __shared__ float wvs[3][2048];

    const int blk = (int)blockIdx.x;
    const int h = blk / 6, b = blk - h * 6;
    const int tid = (int)threadIdx.x;
    const int dg = tid >> 6, eg = tid & 63;

    // ---- issue C loads first: 16 x global_load_dwordx4, deep batch ----
    const float4* Cv = (const float4*)C + (((b << 8) + (dg << 4)) << 6) + eg;
    float4 m4[16];
    #pragma unroll
    for (int i = 0; i < 16; ++i) m4[i] = Cv[i << 6];

    // ---- init (overlaps with C-load drain) ----
    if (tid < 256) vbuf[0][tid] = P2[(h * 6 + b) * 256 + tid];
    if (tid < 768) {
        int s = tid >> 8, ee = tid & 255;
        float fr = (s == 0) ? f1[0]  : (s == 1) ? f2[0]  : f3[0];
        float ph = (s == 0) ? ph1[0] : (s == 1) ? ph2[0] : ph3[0];
        float sn = sinf((float)ee * TWO_PI * fr + ph);
        float mm = sn * sn * 0.1f + 0.95f;
        modl[s][ee] = (s == 1) ? mm : 1.0f / mm;   // s0: /m, s1: *m, s2: /m
    }
    const int nwl = cnt[b];
    for (int i = tid; i < nwl; i += 1024) {
        wde[i]    = wde_g[b * 2048 + i];
        wvs[0][i] = wv_g[(0 * 6 + b) * 2048 + i];
        wvs[1][i] = wv_g[(1 * 6 + b) * 2048 + i];
        wvs[2][i] = wv_g[(2 * 6 + b) * 2048 + i];
    }
    __syncthreads();

    int cur = 0;
    for (int s = 0; s < 3; ++s) {
        const float* vin = vbuf[cur];
        float* vout = vbuf[cur ^ 1];
        float4 acc = make_float4(0.f, 0.f, 0.f, 0.f);
        #pragma unroll
        for (int j = 0; j < 4; ++j) {
            float4 vv = *(const float4*)&vin[(dg << 4) + (j << 2)];
            float4 m0 = m4[(j << 2) + 0];
            float4 m1 = m4[(j << 2) + 1];
            float4 m2 = m4[(j << 2) + 2];
            float4 m3 = m4[(j << 2) + 3];
            acc.x = fmaf(vv.x, m0.x, acc.x); acc.y = fmaf(vv.x, m0.y, acc.y);
            acc.z = fmaf(vv.x, m0.z, acc.z); acc.w = fmaf(vv.x, m0.w, acc.w);
            acc.x = fmaf(vv.y, m1.x, acc.x); acc.y = fmaf(vv.y, m1.y, acc.y);
            acc.z = fmaf(vv.y, m1.z, acc.z); acc.w = fmaf(vv.y, m1.w, acc.w);
            acc.x = fmaf(vv.z, m2.x, acc.x); acc.y = fmaf(vv.z, m2.y, acc.y);
            acc.z = fmaf(vv.z, m2.z, acc.z); acc.w = fmaf(vv.z, m2.w, acc.w);
            acc.x = fmaf(vv.w, m3.x, acc.x); acc.y = fmaf(vv.w, m3.y, acc.y);
            acc.z = fmaf(vv.w, m3.z, acc.z); acc.w = fmaf(vv.w, m3.w, acc.w);
        }
        *(float4*)&pv[dg][eg << 2] = acc;
        __syncthreads();
        if (tid < 256) {                      // 16->1 reduce, modl folded
            float x = 0.f;
            #pragma unroll
            for (int r = 0; r < 16; ++r) x += pv[r][tid];
            vout[tid] = x * modl[s][tid];
        }
        __syncthreads();
        for (int i = tid; i < nwl; i += 1024) {
            int de = wde[i];
            atomicAdd(&vout[de & 255],
                      vin[de >> 8] * wvs[s][i] * modl[s][de & 255]);
        }
        __syncthreads();
        cur ^= 1;
    }
    if (tid < 256) out[(h * 6 + b) * 256 + tid] = vbuf[cur][tid];
}

extern "C" void kernel_launch(void* const* d_in, const int* in_sizes, int n_in,
                              void* d_out, int out_size, void* d_ws, size_t ws_size,
                              hipStream_t stream)
{
    (void)n_in; (void)out_size; (void)ws_size;
    const float* P1  = (const float*)d_in[0];
    const float* P2  = (const float*)d_in[1];
    const float* P3  = (const float*)d_in[2];
    const float* T4  = (const float*)d_in[3];
    const int*   p5  = (const int*)d_in[4];
    const int*   p6  = (const int*)d_in[5];
    const int*   p7  = (const int*)d_in[6];
    const int*   p8  = (const int*)d_in[7];
    const float* f1  = (const float*)d_in[8];
    const float* ph1 = (const float*)d_in[9];
    const float* T11 = (const float*)d_in[10];
    const float* f2  = (const float*)d_in[11];
    const float* ph2 = (const float*)d_in[12];
    const float* T14 = (const float*)d_in[13];
    const float* f3  = (const float*)d_in[14];
    const float* ph3 = (const float*)d_in[15];
    float* out = (float*)d_out;
    int K = in_sizes[4];

    char* ws = (char*)d_ws;
    float* C     = (float*)(ws);
    int*   cnt   = (int*)  (ws + 1572864);
    int*   wde_g = (int*)  (ws + 1572928);
    float* wv_g  = (float*)(ws + 1622080);

    hipLaunchKernelGGL(prep_kernel, dim3(97), dim3(1024), 0, stream,
                       P1, P3, p5, p6, p7, p8, T4, T11, T14,
                       C, cnt, wde_g, wv_g, K);
    hipLaunchKernelGGL(chain_kernel, dim3(72), dim3(1024), 0, stream,
                       C, P2, cnt, wde_g, wv_g,
                       f1, ph1, f2, ph2, f3, ph3, out);
}